// Round 6
// baseline (473.499 us; speedup 1.0000x reference)
//
#include <hip/hip_runtime.h>
#include <hip/hip_fp16.h>

// GCNEncoder: two GCNConv(+relu) layers + global mean pool.
// N=50000 nodes, E=1.6M edges, 128 ch, 64 graphs.
// R5: channel-chunked aggregation (4 x 32ch, xw tile 3.2MB fits per-XCD L2),
// edge list packed to 4B {src:17, f16 norm:15}, nontemporal edge streaming.

#define CH 128
#define BSH 7        // 128 nodes per bucket
#define NBLK 256     // level-1 edge-chunk blocks
#define MAXNB 512    // LDS histogram capacity (NB = ceil(N/128) = 391)
#define PCH 32       // pool chunks per graph
#define TCH 4        // channel chunks (32 ch each)

static __device__ __forceinline__ unsigned short f2bf(float f) {
    unsigned u = __float_as_uint(f);
    unsigned r = (u + 0x7FFF + ((u >> 16) & 1)) >> 16;  // RNE
    return (unsigned short)r;
}
static __device__ __forceinline__ float bflo(unsigned v) { return __uint_as_float(v << 16); }
static __device__ __forceinline__ float bfhi(unsigned v) { return __uint_as_float(v & 0xFFFF0000u); }
static __device__ __forceinline__ float f16u(unsigned p) {
    __half_raw hr; hr.x = (unsigned short)(p & 0x7FFF);
    return __half2float(*reinterpret_cast<__half*>(&hr));
}

// ---- level-1 count: per-(bucket, chunk-block) histogram, LDS atomics only
__global__ __launch_bounds__(256) void k_sort1a(const int* __restrict__ col,
                                                int* __restrict__ H, int E, int NB, int chunk) {
    __shared__ int hist[MAXNB];
    int t = threadIdx.x, blk = blockIdx.x;
    for (int i = t; i < NB; i += 256) hist[i] = 0;
    __syncthreads();
    int s = blk * chunk, e1 = min(s + chunk, E);
    for (int e = s + t; e < e1; e += 256) atomicAdd(&hist[col[e] >> BSH], 1);
    __syncthreads();
    for (int i = t; i < NB; i += 256) H[(size_t)i * NBLK + blk] = hist[i];
}

// ---- 3-phase exclusive scan, in place over data[0..n) ----
__global__ __launch_bounds__(1024) void k_scan1(int* __restrict__ data,
                                                int* __restrict__ bsum, int n) {
    __shared__ int sd[1024];
    int t = threadIdx.x;
    int i = blockIdx.x * 1024 + t;
    int v = (i < n) ? data[i] : 0;
    sd[t] = v;
    __syncthreads();
    for (int off = 1; off < 1024; off <<= 1) {
        int u = (t >= off) ? sd[t - off] : 0;
        __syncthreads();
        sd[t] += u;
        __syncthreads();
    }
    if (i < n) data[i] = sd[t] - v;
    if (t == 1023) bsum[blockIdx.x] = sd[1023];
}

__global__ __launch_bounds__(64) void k_scan2(int* bsum, int nb, int* total) {
    int t = threadIdx.x;
    if (nb <= 64) {
        int v = (t < nb) ? bsum[t] : 0;
        int orig = v;
        for (int off = 1; off < 64; off <<= 1) {
            int u = __shfl_up(v, off);
            if (t >= off) v += u;
        }
        if (t < nb) bsum[t] = v - orig;
        if (t == nb - 1) *total = v;
    } else if (t == 0) {
        int run = 0;
        for (int i = 0; i < nb; ++i) { int c = bsum[i]; bsum[i] = run; run += c; }
        *total = run;
    }
}

__global__ void k_scan3(int* data, const int* __restrict__ bsum, int n) {
    int i = blockIdx.x * 256 + threadIdx.x;
    if (i < n) data[i] += bsum[i >> 10];
}

// ---- level-1 scatter into bucket order via LDS cursors (disjoint regions)
__global__ __launch_bounds__(256) void k_sort1b(const int* __restrict__ row,
                                                const int* __restrict__ col,
                                                const float* __restrict__ ew,
                                                const int* __restrict__ Hs,
                                                int* __restrict__ cbuf,
                                                int2* __restrict__ pairs2,
                                                int E, int NB, int chunk) {
    __shared__ int cur[MAXNB];
    int t = threadIdx.x, blk = blockIdx.x;
    for (int i = t; i < NB; i += 256) cur[i] = Hs[(size_t)i * NBLK + blk];
    __syncthreads();
    int s = blk * chunk, e1 = min(s + chunk, E);
    for (int e = s + t; e < e1; e += 256) {
        int c = col[e];
        int pos = atomicAdd(&cur[c >> BSH], 1);
        cbuf[pos] = c;
        pairs2[pos] = make_int2(row[e], __float_as_int(ew[e]));
    }
}

// ---- level-2: per-bucket node sort + rowptr + degree (dis), LDS only
__global__ __launch_bounds__(256) void k_sort2(const int* __restrict__ Hs,
                                               const int* __restrict__ cbuf,
                                               const int2* __restrict__ pairs2,
                                               int2* __restrict__ pairs,
                                               int* __restrict__ rowptr,
                                               float* __restrict__ dis,
                                               int E, int N, int NB) {
    __shared__ int hist[128];
    __shared__ int pref[128];
    __shared__ float wsum[128];
    int b = blockIdx.x, t = threadIdx.x;
    int n0 = b << BSH;
    int s = Hs[(size_t)b * NBLK];
    int e1 = (b + 1 < NB) ? Hs[(size_t)(b + 1) * NBLK] : E;
    if (t < 128) { hist[t] = 0; wsum[t] = 0.f; }
    __syncthreads();
    for (int e = s + t; e < e1; e += 256) atomicAdd(&hist[cbuf[e] - n0], 1);
    __syncthreads();
    if (t < 128) pref[t] = hist[t];
    __syncthreads();
    for (int off = 1; off < 128; off <<= 1) {
        int v = 0;
        if (t < 128 && t >= off) v = pref[t - off];
        __syncthreads();
        if (t < 128) pref[t] += v;
        __syncthreads();
    }
    if (t < 128) {
        int excl = pref[t] - hist[t];
        int node = n0 + t;
        if (node < N) rowptr[node] = s + excl;
        hist[t] = s + excl;  // cursor
    }
    if (b == NB - 1 && t == 0) rowptr[N] = E;
    __syncthreads();
    for (int e = s + t; e < e1; e += 256) {
        int li = cbuf[e] - n0;
        int2 pr = pairs2[e];
        int pos = atomicAdd(&hist[li], 1);
        pairs[pos] = pr;
        atomicAdd(&wsum[li], __int_as_float(pr.y));
    }
    __syncthreads();
    if (t < 128 && n0 + t < N) dis[n0 + t] = rsqrtf(1.0f + wsum[t]);
}

// epk[e] = {src:17 bits}<<15 | f16(norm) magnitude (norm > 0 always)
__global__ __launch_bounds__(64) void k_norm(const int* __restrict__ rowptr,
                                             const int2* __restrict__ pairs,
                                             const float* __restrict__ dis,
                                             unsigned* __restrict__ epk, int N) {
    int n = blockIdx.x;
    int lane = threadIdx.x;
    float dn = dis[n];
    int e0 = rowptr[n], e1 = rowptr[n + 1];
    for (int e = e0 + lane; e < e1; e += 64) {
        int2 p = pairs[e];
        float nn = dn * __int_as_float(p.y) * dis[p.x];
        __half hh = __float2half(nn);
        unsigned short hb = *reinterpret_cast<unsigned short*>(&hh);
        epk[e] = ((unsigned)p.x << 15) | (unsigned)(hb & 0x7FFF);
    }
}

// Y (chunk-major [TCH][N][32] bf16) = X[N,128](f32) @ W[128,128](f32).
__global__ __launch_bounds__(256) void k_gemm(const float* __restrict__ X,
                                              const float* __restrict__ W,
                                              unsigned short* __restrict__ Y, int N) {
    __shared__ float Ws[128][128];
    __shared__ float Xs[32][128];
    int tid = threadIdx.x;
    {
        const float4* Wv = (const float4*)W;
        float4* Sv = (float4*)&Ws[0][0];
#pragma unroll
        for (int i = 0; i < 16; ++i) Sv[tid + 256 * i] = Wv[tid + 256 * i];
    }
    int row0 = blockIdx.x * 32;
    {
        float4* Xsv = (float4*)&Xs[0][0];
        if (row0 + 32 <= N) {
            const float4* Xv = (const float4*)(X + (size_t)row0 * CH);
#pragma unroll
            for (int i = 0; i < 4; ++i) { int idx = tid + 256 * i; Xsv[idx] = Xv[idx]; }
        } else {
#pragma unroll
            for (int i = 0; i < 4; ++i) {
                int idx = tid + 256 * i;
                int r = idx >> 5;
                float4 v = make_float4(0.f, 0.f, 0.f, 0.f);
                if (row0 + r < N) v = ((const float4*)(X + (size_t)(row0 + r) * CH))[idx & 31];
                Xsv[idx] = v;
            }
        }
    }
    __syncthreads();
    int c4 = tid & 31;
    int rl = tid >> 5;
    float4 acc[4];
#pragma unroll
    for (int j = 0; j < 4; ++j) acc[j] = make_float4(0.f, 0.f, 0.f, 0.f);
    for (int k = 0; k < 128; k += 4) {
        float4 w0 = *(const float4*)&Ws[k + 0][c4 * 4];
        float4 w1 = *(const float4*)&Ws[k + 1][c4 * 4];
        float4 w2 = *(const float4*)&Ws[k + 2][c4 * 4];
        float4 w3 = *(const float4*)&Ws[k + 3][c4 * 4];
#pragma unroll
        for (int j = 0; j < 4; ++j) {
            float4 xv = *(const float4*)&Xs[rl + 8 * j][k];
            acc[j].x += xv.x * w0.x + xv.y * w1.x + xv.z * w2.x + xv.w * w3.x;
            acc[j].y += xv.x * w0.y + xv.y * w1.y + xv.z * w2.y + xv.w * w3.y;
            acc[j].z += xv.x * w0.z + xv.y * w1.z + xv.z * w2.z + xv.w * w3.z;
            acc[j].w += xv.x * w0.w + xv.y * w1.w + xv.z * w2.w + xv.w * w3.w;
        }
    }
    int c  = c4 >> 3;            // channel chunk
    int of = (c4 & 7) * 4;       // ushort offset within chunk row
#pragma unroll
    for (int j = 0; j < 4; ++j) {
        int r = row0 + rl + 8 * j;
        if (r < N) {
            ushort4 o;
            o.x = f2bf(acc[j].x); o.y = f2bf(acc[j].y);
            o.z = f2bf(acc[j].z); o.w = f2bf(acc[j].w);
            *(ushort4*)&Y[(size_t)c * N * 32 + (size_t)r * 32 + of] = o;
        }
    }
}

// Chunked aggregation: 32 channels per dispatch. 4 nodes/block (4 waves).
// Wave = 4 groups x 16 lanes; each group streams every 4th edge, 16 lanes
// gather 64B of the per-XCD-L2-resident xw tile. Cross-group shfl reduce.
__global__ __launch_bounds__(256) void k_aggc(const unsigned int* __restrict__ XWC,
                                              const float* __restrict__ dis,
                                              const int* __restrict__ rowptr,
                                              const unsigned int* __restrict__ epk,
                                              const float* __restrict__ bias,
                                              float* __restrict__ OUT,
                                              int col0, int N) {
    int n = blockIdx.x * 4 + (threadIdx.x >> 6);
    if (n >= N) return;
    int lane = threadIdx.x & 63;
    int g  = lane >> 4;
    int li = lane & 15;
    float ax = 0.f, ay = 0.f;
    int e0 = rowptr[n], e1 = rowptr[n + 1];
    int e = e0 + g;
    for (; e + 4 < e1; e += 8) {
        unsigned p0 = __builtin_nontemporal_load(&epk[e]);
        unsigned p1 = __builtin_nontemporal_load(&epk[e + 4]);
        unsigned v0 = XWC[(size_t)(p0 >> 15) * 16 + li];
        unsigned v1 = XWC[(size_t)(p1 >> 15) * 16 + li];
        float n0 = f16u(p0), n1 = f16u(p1);
        ax += n0 * bflo(v0) + n1 * bflo(v1);
        ay += n0 * bfhi(v0) + n1 * bfhi(v1);
    }
    if (e < e1) {
        unsigned p = __builtin_nontemporal_load(&epk[e]);
        unsigned v = XWC[(size_t)(p >> 15) * 16 + li];
        float nn = f16u(p);
        ax += nn * bflo(v);
        ay += nn * bfhi(v);
    }
    if (g == 0) {  // self-loop term
        float d = dis[n];
        float sn = d * d;
        unsigned a = XWC[(size_t)n * 16 + li];
        ax += sn * bflo(a);
        ay += sn * bfhi(a);
    }
    ax += __shfl_xor(ax, 16); ay += __shfl_xor(ay, 16);
    ax += __shfl_xor(ax, 32); ay += __shfl_xor(ay, 32);
    if (g == 0) {
        float2 b = *(const float2*)&bias[col0 + li * 2];
        ax = fmaxf(ax + b.x, 0.f);
        ay = fmaxf(ay + b.y, 0.f);
        *(float2*)&OUT[(size_t)n * CH + col0 + li * 2] = make_float2(ax, ay);
    }
}

__device__ __forceinline__ int lowerb(const int* a, int n, int v) {
    int lo = 0, hi = n;
    while (lo < hi) {
        int m = (lo + hi) >> 1;
        if (a[m] < v) lo = m + 1; else hi = m;
    }
    return lo;
}

// Stage 1: 64 graphs x PCH chunks, partial channel sums.
__global__ __launch_bounds__(128) void k_pool1(const float* __restrict__ H,
                                               const int* __restrict__ batch,
                                               float* __restrict__ partial, int N) {
    __shared__ int ss[2];
    int g = blockIdx.x / PCH;
    int k = blockIdx.x % PCH;
    if (threadIdx.x == 0) {
        ss[0] = lowerb(batch, N, g);
        ss[1] = lowerb(batch, N, g + 1);
    }
    __syncthreads();
    int s = ss[0], len = ss[1] - ss[0];
    int cs = s + (int)(((long long)len * k) / PCH);
    int ce = s + (int)(((long long)len * (k + 1)) / PCH);
    int ch = threadIdx.x;
    float a0 = 0.f, a1 = 0.f;
    int n = cs;
    for (; n + 2 <= ce; n += 2) {
        a0 += H[(size_t)(n + 0) * CH + ch];
        a1 += H[(size_t)(n + 1) * CH + ch];
    }
    for (; n < ce; ++n) a0 += H[(size_t)n * CH + ch];
    partial[(size_t)blockIdx.x * CH + ch] = a0 + a1;
}

// Stage 2: reduce PCH partials per graph, divide by count.
__global__ __launch_bounds__(128) void k_pool2(const float* __restrict__ partial,
                                               const int* __restrict__ batch,
                                               float* __restrict__ P, int N) {
    __shared__ int ss[2];
    int g = blockIdx.x;
    if (threadIdx.x == 0) {
        ss[0] = lowerb(batch, N, g);
        ss[1] = lowerb(batch, N, g + 1);
    }
    __syncthreads();
    int ch = threadIdx.x;
    float a = 0.f;
#pragma unroll
    for (int k = 0; k < PCH; ++k) a += partial[(size_t)(g * PCH + k) * CH + ch];
    float c = (float)(ss[1] - ss[0]);
    P[(size_t)g * CH + ch] = a / fmaxf(c, 1.f);
}

extern "C" void kernel_launch(void* const* d_in, const int* in_sizes, int n_in,
                              void* d_out, int out_size, void* d_ws, size_t ws_size,
                              hipStream_t stream) {
    const float* x     = (const float*)d_in[0];
    const int*   ei    = (const int*)d_in[1];
    const float* ew    = (const float*)d_in[2];
    const int*   batch = (const int*)d_in[3];
    const float* W1    = (const float*)d_in[4];
    const float* b1    = (const float*)d_in[5];
    const float* W2    = (const float*)d_in[6];
    const float* b2    = (const float*)d_in[7];

    int N = in_sizes[0] / CH;   // 50000
    int E = in_sizes[1] / 2;    // 1600000
    const int* row = ei;
    const int* col = ei + E;

    float* out    = (float*)d_out;
    float* h      = out;
    float* pooled = out + (size_t)N * CH;

    int NB    = (N + 127) >> BSH;          // 391
    int chunk = (E + NBLK - 1) / NBLK;     // 6250
    int n2    = NB * NBLK;                 // 100096

    // ws: dis | rowptr | H(n2+1) | bsum | pairs | cbuf(epk/partial alias) | xw
    char* wsb = (char*)d_ws;
    size_t oN  = ((size_t)N * 4 + 255) & ~(size_t)255;
    size_t oN1 = ((size_t)(N + 1) * 4 + 255) & ~(size_t)255;
    size_t oH  = ((size_t)(n2 + 1) * 4 + 255) & ~(size_t)255;
    size_t oB  = 512;
    size_t oE2 = ((size_t)E * 8 + 255) & ~(size_t)255;
    size_t oE1 = ((size_t)E * 4 + 255) & ~(size_t)255;
    float* dis    = (float*)wsb;
    int*   rowptr = (int*)(wsb + oN);
    int*   H      = (int*)(wsb + oN + oN1);
    int*   bsum   = (int*)(wsb + oN + oN1 + oH);
    int2*  pairs  = (int2*)(wsb + oN + oN1 + oH + oB);
    int*   cbuf   = (int*)(wsb + oN + oN1 + oH + oB + oE2);
    unsigned short* xw = (unsigned short*)(wsb + oN + oN1 + oH + oB + oE2 + oE1);
    int2*  pairs2 = (int2*)xw;          // dead before k_gemm writes xw
    unsigned* epk = (unsigned*)cbuf;    // cbuf dead after sort2
    float* partial = (float*)cbuf;      // epk dead before pool1

    int sb2 = (n2 + 1023) / 1024;

    // ---- CSR build: two-level LDS counting sort (no global atomics) ----
    k_sort1a<<<NBLK, 256, 0, stream>>>(col, H, E, NB, chunk);
    k_scan1<<<sb2, 1024, 0, stream>>>(H, bsum, n2);
    k_scan2<<<1, 64, 0, stream>>>(bsum, sb2, H + n2);
    k_scan3<<<(n2 + 255) / 256, 256, 0, stream>>>(H, bsum, n2);
    k_sort1b<<<NBLK, 256, 0, stream>>>(row, col, ew, H, cbuf, pairs2, E, NB, chunk);
    k_sort2<<<NB, 256, 0, stream>>>(H, cbuf, pairs2, pairs, rowptr, dis, E, N, NB);
    k_norm<<<N, 64, 0, stream>>>(rowptr, pairs, dis, epk, N);

    int gb = (N + 31) / 32;
    int ab = (N + 3) / 4;
    // ---- layer 1 ----
    k_gemm<<<gb, 256, 0, stream>>>(x, W1, xw, N);
    for (int c = 0; c < TCH; ++c)
        k_aggc<<<ab, 256, 0, stream>>>((const unsigned int*)(xw + (size_t)c * N * 32),
                                       dis, rowptr, epk, b1, h, c * 32, N);
    // ---- layer 2 ----
    k_gemm<<<gb, 256, 0, stream>>>(h, W2, xw, N);
    for (int c = 0; c < TCH; ++c)
        k_aggc<<<ab, 256, 0, stream>>>((const unsigned int*)(xw + (size_t)c * N * 32),
                                       dis, rowptr, epk, b2, h, c * 32, N);
    // ---- mean pool (two-stage) ----
    k_pool1<<<64 * PCH, 128, 0, stream>>>(h, batch, partial, N);
    k_pool2<<<64, 128, 0, stream>>>(partial, batch, pooled, N);
}

// Round 7
// 261.313 us; speedup vs baseline: 1.8120x; 1.8120x over previous
//
#include <hip/hip_runtime.h>

// GCNEncoder: two GCNConv(+relu) layers + global mean pool.
// N=50000 nodes, E=1.6M edges, 128 ch, 64 graphs.
// R6: revert channel-chunked agg (R5 regression: 64B gathers + low MLP).
// Fix k_sort1b: NBLK 256->1024 (occupancy 7.5%->~40%), single 8B packed
// store per edge (li packed into src's spare bits), cbuf eliminated.

#define CH 128
#define BSH 7         // 128 nodes per bucket
#define NBLK 1024     // level-1 edge-chunk blocks
#define MAXNB 512     // LDS histogram capacity (NB = ceil(N/128) = 391)
#define PCH 32        // pool chunks per graph

static __device__ __forceinline__ unsigned short f2bf(float f) {
    unsigned u = __float_as_uint(f);
    unsigned r = (u + 0x7FFF + ((u >> 16) & 1)) >> 16;  // RNE
    return (unsigned short)r;
}

// ---- level-1 count: per-(bucket, chunk-block) histogram, LDS atomics only
__global__ __launch_bounds__(256) void k_sort1a(const int* __restrict__ col,
                                                int* __restrict__ H, int E, int NB, int chunk) {
    __shared__ int hist[MAXNB];
    int t = threadIdx.x, blk = blockIdx.x;
    for (int i = t; i < NB; i += 256) hist[i] = 0;
    __syncthreads();
    int s = blk * chunk, e1 = min(s + chunk, E);
    for (int e = s + t; e < e1; e += 256) atomicAdd(&hist[col[e] >> BSH], 1);
    __syncthreads();
    for (int i = t; i < NB; i += 256) H[(size_t)i * NBLK + blk] = hist[i];
}

// ---- 3-phase exclusive scan, in place over data[0..n) ----
__global__ __launch_bounds__(1024) void k_scan1(int* __restrict__ data,
                                                int* __restrict__ bsum, int n) {
    __shared__ int sd[1024];
    int t = threadIdx.x;
    int i = blockIdx.x * 1024 + t;
    int v = (i < n) ? data[i] : 0;
    sd[t] = v;
    __syncthreads();
    for (int off = 1; off < 1024; off <<= 1) {
        int u = (t >= off) ? sd[t - off] : 0;
        __syncthreads();
        sd[t] += u;
        __syncthreads();
    }
    if (i < n) data[i] = sd[t] - v;
    if (t == 1023) bsum[blockIdx.x] = sd[1023];
}

// single-block LDS exclusive scan over bsum[0..nb), nb <= 1024
__global__ __launch_bounds__(1024) void k_scan2(int* bsum, int nb, int* total) {
    __shared__ int sd[1024];
    int t = threadIdx.x;
    int v = (t < nb) ? bsum[t] : 0;
    sd[t] = v;
    __syncthreads();
    for (int off = 1; off < 1024; off <<= 1) {
        int u = (t >= off) ? sd[t - off] : 0;
        __syncthreads();
        sd[t] += u;
        __syncthreads();
    }
    if (t < nb) bsum[t] = sd[t] - v;
    if (t == 1023) *total = sd[1023];
}

__global__ void k_scan3(int* data, const int* __restrict__ bsum, int n) {
    int i = blockIdx.x * 256 + threadIdx.x;
    if (i < n) data[i] += bsum[i >> 10];
}

// ---- level-1 scatter into bucket order via LDS cursors (disjoint regions)
// pairs2[pos] = { src | (c&127)<<17 , weight } — one aligned 8B store/edge.
__global__ __launch_bounds__(256) void k_sort1b(const int* __restrict__ row,
                                                const int* __restrict__ col,
                                                const float* __restrict__ ew,
                                                const int* __restrict__ Hs,
                                                int2* __restrict__ pairs2,
                                                int E, int NB, int chunk) {
    __shared__ int cur[MAXNB];
    int t = threadIdx.x, blk = blockIdx.x;
    for (int i = t; i < NB; i += 256) cur[i] = Hs[(size_t)i * NBLK + blk];
    __syncthreads();
    int s = blk * chunk, e1 = min(s + chunk, E);
    for (int e = s + t; e < e1; e += 256) {
        int c = col[e];
        int pos = atomicAdd(&cur[c >> BSH], 1);
        pairs2[pos] = make_int2(row[e] | ((c & 127) << 17), __float_as_int(ew[e]));
    }
}

// ---- level-2: per-bucket node sort + rowptr + degree (dis), LDS only
__global__ __launch_bounds__(256) void k_sort2(const int* __restrict__ Hs,
                                               const int2* __restrict__ pairs2,
                                               int2* __restrict__ pairs,
                                               int* __restrict__ rowptr,
                                               float* __restrict__ dis,
                                               int E, int N, int NB) {
    __shared__ int hist[128];
    __shared__ int pref[128];
    __shared__ float wsum[128];
    int b = blockIdx.x, t = threadIdx.x;
    int n0 = b << BSH;
    int s = Hs[(size_t)b * NBLK];
    int e1 = (b + 1 < NB) ? Hs[(size_t)(b + 1) * NBLK] : E;
    if (t < 128) { hist[t] = 0; wsum[t] = 0.f; }
    __syncthreads();
    for (int e = s + t; e < e1; e += 256)
        atomicAdd(&hist[(unsigned)pairs2[e].x >> 17], 1);
    __syncthreads();
    if (t < 128) pref[t] = hist[t];
    __syncthreads();
    for (int off = 1; off < 128; off <<= 1) {
        int v = 0;
        if (t < 128 && t >= off) v = pref[t - off];
        __syncthreads();
        if (t < 128) pref[t] += v;
        __syncthreads();
    }
    if (t < 128) {
        int excl = pref[t] - hist[t];
        int node = n0 + t;
        if (node < N) rowptr[node] = s + excl;
        hist[t] = s + excl;  // cursor
    }
    if (b == NB - 1 && t == 0) rowptr[N] = E;
    __syncthreads();
    for (int e = s + t; e < e1; e += 256) {
        int2 pr = pairs2[e];
        int li = (unsigned)pr.x >> 17;
        int pos = atomicAdd(&hist[li], 1);
        pairs[pos] = make_int2(pr.x & 0x1FFFF, pr.y);
        atomicAdd(&wsum[li], __int_as_float(pr.y));
    }
    __syncthreads();
    if (t < 128 && n0 + t < N) dis[n0 + t] = rsqrtf(1.0f + wsum[t]);
}

// pairs[e].y: weight -> norm = dis[n] * w * dis[src]
__global__ __launch_bounds__(64) void k_norm(const int* __restrict__ rowptr,
                                             int2* __restrict__ pairs,
                                             const float* __restrict__ dis, int N) {
    int n = blockIdx.x;
    int lane = threadIdx.x;
    float dn = dis[n];
    int e0 = rowptr[n], e1 = rowptr[n + 1];
    for (int e = e0 + lane; e < e1; e += 64) {
        int2 p = pairs[e];
        float nn = dn * __int_as_float(p.y) * dis[p.x];
        pairs[e].y = __float_as_int(nn);
    }
}

// Y[N,128](bf16) = X[N,128](f32) @ W[128,128](f32). W + 32-row X tile in LDS.
__global__ __launch_bounds__(256) void k_gemm(const float* __restrict__ X,
                                              const float* __restrict__ W,
                                              unsigned short* __restrict__ Y, int N) {
    __shared__ float Ws[128][128];
    __shared__ float Xs[32][128];
    int tid = threadIdx.x;
    {
        const float4* Wv = (const float4*)W;
        float4* Sv = (float4*)&Ws[0][0];
#pragma unroll
        for (int i = 0; i < 16; ++i) Sv[tid + 256 * i] = Wv[tid + 256 * i];
    }
    int row0 = blockIdx.x * 32;
    {
        float4* Xsv = (float4*)&Xs[0][0];
        if (row0 + 32 <= N) {
            const float4* Xv = (const float4*)(X + (size_t)row0 * CH);
#pragma unroll
            for (int i = 0; i < 4; ++i) { int idx = tid + 256 * i; Xsv[idx] = Xv[idx]; }
        } else {
#pragma unroll
            for (int i = 0; i < 4; ++i) {
                int idx = tid + 256 * i;
                int r = idx >> 5;
                float4 v = make_float4(0.f, 0.f, 0.f, 0.f);
                if (row0 + r < N) v = ((const float4*)(X + (size_t)(row0 + r) * CH))[idx & 31];
                Xsv[idx] = v;
            }
        }
    }
    __syncthreads();
    int c4 = tid & 31;
    int rl = tid >> 5;
    float4 acc[4];
#pragma unroll
    for (int j = 0; j < 4; ++j) acc[j] = make_float4(0.f, 0.f, 0.f, 0.f);
    for (int k = 0; k < 128; k += 4) {
        float4 w0 = *(const float4*)&Ws[k + 0][c4 * 4];
        float4 w1 = *(const float4*)&Ws[k + 1][c4 * 4];
        float4 w2 = *(const float4*)&Ws[k + 2][c4 * 4];
        float4 w3 = *(const float4*)&Ws[k + 3][c4 * 4];
#pragma unroll
        for (int j = 0; j < 4; ++j) {
            float4 xv = *(const float4*)&Xs[rl + 8 * j][k];
            acc[j].x += xv.x * w0.x + xv.y * w1.x + xv.z * w2.x + xv.w * w3.x;
            acc[j].y += xv.x * w0.y + xv.y * w1.y + xv.z * w2.y + xv.w * w3.y;
            acc[j].z += xv.x * w0.z + xv.y * w1.z + xv.z * w2.z + xv.w * w3.z;
            acc[j].w += xv.x * w0.w + xv.y * w1.w + xv.z * w2.w + xv.w * w3.w;
        }
    }
#pragma unroll
    for (int j = 0; j < 4; ++j) {
        int r = row0 + rl + 8 * j;
        if (r < N) {
            ushort4 o;
            o.x = f2bf(acc[j].x); o.y = f2bf(acc[j].y);
            o.z = f2bf(acc[j].z); o.w = f2bf(acc[j].w);
            *(ushort4*)&Y[(size_t)r * CH + c4 * 4] = o;
        }
    }
}

// One wave per node: out[n] = relu( selfnorm*xw[n] + sum_e nrm_e*xw[src_e] + b ).
// xw is bf16 (2 ch per lane = 4B/lane, 256B/edge gather); accumulate fp32.
__global__ __launch_bounds__(64) void k_agg(const unsigned int* __restrict__ XW,
                                            const float* __restrict__ dis,
                                            const int* __restrict__ rowptr,
                                            const int2* __restrict__ pairs,
                                            const float* __restrict__ bias,
                                            float* __restrict__ OUT, int N) {
    int n = blockIdx.x;
    if (n >= N) return;
    int lane = threadIdx.x;
    float d = dis[n];
    float sn = d * d;
    unsigned a = XW[(size_t)n * 64 + lane];
    float ax = __uint_as_float(a << 16) * sn;
    float ay = __uint_as_float(a & 0xFFFF0000u) * sn;
    int e0 = rowptr[n], e1 = rowptr[n + 1];
    int e = e0;
    for (; e + 4 <= e1; e += 4) {
        int2 p0 = pairs[e], p1 = pairs[e + 1], p2 = pairs[e + 2], p3 = pairs[e + 3];
        unsigned v0 = XW[(size_t)p0.x * 64 + lane];
        unsigned v1 = XW[(size_t)p1.x * 64 + lane];
        unsigned v2 = XW[(size_t)p2.x * 64 + lane];
        unsigned v3 = XW[(size_t)p3.x * 64 + lane];
        float n0 = __int_as_float(p0.y), n1 = __int_as_float(p1.y);
        float n2 = __int_as_float(p2.y), n3 = __int_as_float(p3.y);
        ax += n0 * __uint_as_float(v0 << 16) + n1 * __uint_as_float(v1 << 16)
            + n2 * __uint_as_float(v2 << 16) + n3 * __uint_as_float(v3 << 16);
        ay += n0 * __uint_as_float(v0 & 0xFFFF0000u) + n1 * __uint_as_float(v1 & 0xFFFF0000u)
            + n2 * __uint_as_float(v2 & 0xFFFF0000u) + n3 * __uint_as_float(v3 & 0xFFFF0000u);
    }
    for (; e < e1; ++e) {
        int2 p = pairs[e];
        unsigned v = XW[(size_t)p.x * 64 + lane];
        float nn = __int_as_float(p.y);
        ax += nn * __uint_as_float(v << 16);
        ay += nn * __uint_as_float(v & 0xFFFF0000u);
    }
    float2 b = ((const float2*)bias)[lane];
    ax = fmaxf(ax + b.x, 0.f);
    ay = fmaxf(ay + b.y, 0.f);
    ((float2*)OUT)[(size_t)n * 64 + lane] = make_float2(ax, ay);
}

__device__ __forceinline__ int lowerb(const int* a, int n, int v) {
    int lo = 0, hi = n;
    while (lo < hi) {
        int m = (lo + hi) >> 1;
        if (a[m] < v) lo = m + 1; else hi = m;
    }
    return lo;
}

// Stage 1: 64 graphs x PCH chunks, partial channel sums.
__global__ __launch_bounds__(128) void k_pool1(const float* __restrict__ H,
                                               const int* __restrict__ batch,
                                               float* __restrict__ partial, int N) {
    __shared__ int ss[2];
    int g = blockIdx.x / PCH;
    int k = blockIdx.x % PCH;
    if (threadIdx.x == 0) {
        ss[0] = lowerb(batch, N, g);
        ss[1] = lowerb(batch, N, g + 1);
    }
    __syncthreads();
    int s = ss[0], len = ss[1] - ss[0];
    int cs = s + (int)(((long long)len * k) / PCH);
    int ce = s + (int)(((long long)len * (k + 1)) / PCH);
    int ch = threadIdx.x;
    float a0 = 0.f, a1 = 0.f;
    int n = cs;
    for (; n + 2 <= ce; n += 2) {
        a0 += H[(size_t)(n + 0) * CH + ch];
        a1 += H[(size_t)(n + 1) * CH + ch];
    }
    for (; n < ce; ++n) a0 += H[(size_t)n * CH + ch];
    partial[(size_t)blockIdx.x * CH + ch] = a0 + a1;
}

// Stage 2: reduce PCH partials per graph, divide by count.
__global__ __launch_bounds__(128) void k_pool2(const float* __restrict__ partial,
                                               const int* __restrict__ batch,
                                               float* __restrict__ P, int N) {
    __shared__ int ss[2];
    int g = blockIdx.x;
    if (threadIdx.x == 0) {
        ss[0] = lowerb(batch, N, g);
        ss[1] = lowerb(batch, N, g + 1);
    }
    __syncthreads();
    int ch = threadIdx.x;
    float a = 0.f;
#pragma unroll
    for (int k = 0; k < PCH; ++k) a += partial[(size_t)(g * PCH + k) * CH + ch];
    float c = (float)(ss[1] - ss[0]);
    P[(size_t)g * CH + ch] = a / fmaxf(c, 1.f);
}

extern "C" void kernel_launch(void* const* d_in, const int* in_sizes, int n_in,
                              void* d_out, int out_size, void* d_ws, size_t ws_size,
                              hipStream_t stream) {
    const float* x     = (const float*)d_in[0];
    const int*   ei    = (const int*)d_in[1];
    const float* ew    = (const float*)d_in[2];
    const int*   batch = (const int*)d_in[3];
    const float* W1    = (const float*)d_in[4];
    const float* b1    = (const float*)d_in[5];
    const float* W2    = (const float*)d_in[6];
    const float* b2    = (const float*)d_in[7];

    int N = in_sizes[0] / CH;   // 50000
    int E = in_sizes[1] / 2;    // 1600000
    const int* row = ei;
    const int* col = ei + E;

    float* out    = (float*)d_out;
    float* h      = out;
    float* pooled = out + (size_t)N * CH;

    int NB    = (N + 127) >> BSH;          // 391
    int chunk = (E + NBLK - 1) / NBLK;     // 1563
    int n2    = NB * NBLK;                 // 400384

    // ws: dis | rowptr | H(n2+1; partial aliases) | bsum | pairs | xw(pairs2 aliases)
    char* wsb = (char*)d_ws;
    size_t oN  = ((size_t)N * 4 + 255) & ~(size_t)255;
    size_t oN1 = ((size_t)(N + 1) * 4 + 255) & ~(size_t)255;
    size_t oH  = ((size_t)(n2 + 1) * 4 + 255) & ~(size_t)255;
    size_t oB  = 4096;
    size_t oE2 = ((size_t)E * 8 + 255) & ~(size_t)255;
    float* dis    = (float*)wsb;
    int*   rowptr = (int*)(wsb + oN);
    int*   H      = (int*)(wsb + oN + oN1);
    int*   bsum   = (int*)(wsb + oN + oN1 + oH);
    int2*  pairs  = (int2*)(wsb + oN + oN1 + oH + oB);
    unsigned short* xw = (unsigned short*)(wsb + oN + oN1 + oH + oB + oE2);
    int2*  pairs2 = (int2*)xw;     // E*8 = 12.8MB == N*CH*2; dead before k_gemm
    float* partial = (float*)H;    // H dead after sort2; 1MB <= 1.6MB

    int sb2 = (n2 + 1023) / 1024;  // 391

    // ---- CSR build: two-level LDS counting sort (no global atomics) ----
    k_sort1a<<<NBLK, 256, 0, stream>>>(col, H, E, NB, chunk);
    k_scan1<<<sb2, 1024, 0, stream>>>(H, bsum, n2);
    k_scan2<<<1, 1024, 0, stream>>>(bsum, sb2, H + n2);
    k_scan3<<<(n2 + 255) / 256, 256, 0, stream>>>(H, bsum, n2);
    k_sort1b<<<NBLK, 256, 0, stream>>>(row, col, ew, H, pairs2, E, NB, chunk);
    k_sort2<<<NB, 256, 0, stream>>>(H, pairs2, pairs, rowptr, dis, E, N, NB);
    k_norm<<<N, 64, 0, stream>>>(rowptr, pairs, dis, N);

    int gb = (N + 31) / 32;
    // ---- layer 1 ----
    k_gemm<<<gb, 256, 0, stream>>>(x, W1, xw, N);
    k_agg<<<N, 64, 0, stream>>>((const unsigned int*)xw, dis, rowptr, pairs, b1, h, N);
    // ---- layer 2 ----
    k_gemm<<<gb, 256, 0, stream>>>(h, W2, xw, N);
    k_agg<<<N, 64, 0, stream>>>((const unsigned int*)xw, dis, rowptr, pairs, b2, h, N);
    // ---- mean pool (two-stage) ----
    k_pool1<<<64 * PCH, 128, 0, stream>>>(h, batch, partial, N);
    k_pool2<<<64, 128, 0, stream>>>(partial, batch, pooled, N);
}

// Round 8
// 224.963 us; speedup vs baseline: 2.1048x; 1.1616x over previous
//
#include <hip/hip_runtime.h>

// GCNEncoder: two GCNConv(+relu) layers + global mean pool.
// N=50000 nodes, E=1.6M edges, 128 ch, 64 graphs.
// R8: MFMA bf16 GEMM (W^T staged in LDS), k_norm fused into k_agg
// (pairs carry {src,w}; norm computed inline), scan3 folded into
// sort1b/sort2 (bsum added inline), k_agg unrolled to 8 gathers in flight.

#define CH 128
#define BSH 7         // 128 nodes per bucket
#define NBLK 1024     // level-1 edge-chunk blocks
#define MAXNB 512     // LDS histogram capacity (NB = ceil(N/128) = 391)
#define PCH 32        // pool chunks per graph
#define LDW 136       // Wt LDS stride (8-elem aligned for b128, 2-way banks)

typedef __attribute__((ext_vector_type(8))) short bf16x8;
typedef __attribute__((ext_vector_type(4))) float f32x4;

static __device__ __forceinline__ unsigned short f2bf(float f) {
    unsigned u = __float_as_uint(f);
    unsigned r = (u + 0x7FFF + ((u >> 16) & 1)) >> 16;  // RNE
    return (unsigned short)r;
}
static __device__ __forceinline__ float bflo(unsigned v) { return __uint_as_float(v << 16); }
static __device__ __forceinline__ float bfhi(unsigned v) { return __uint_as_float(v & 0xFFFF0000u); }

// ---- level-1 count: per-(bucket, chunk-block) histogram, LDS atomics only
__global__ __launch_bounds__(256) void k_sort1a(const int* __restrict__ col,
                                                int* __restrict__ H, int E, int NB, int chunk) {
    __shared__ int hist[MAXNB];
    int t = threadIdx.x, blk = blockIdx.x;
    for (int i = t; i < NB; i += 256) hist[i] = 0;
    __syncthreads();
    int s = blk * chunk, e1 = min(s + chunk, E);
    for (int e = s + t; e < e1; e += 256) atomicAdd(&hist[col[e] >> BSH], 1);
    __syncthreads();
    for (int i = t; i < NB; i += 256) H[(size_t)i * NBLK + blk] = hist[i];
}

// ---- scan phase 1: block-local exclusive in place, block totals to bsum
__global__ __launch_bounds__(1024) void k_scan1(int* __restrict__ data,
                                                int* __restrict__ bsum, int n) {
    __shared__ int sd[1024];
    int t = threadIdx.x;
    int i = blockIdx.x * 1024 + t;
    int v = (i < n) ? data[i] : 0;
    sd[t] = v;
    __syncthreads();
    for (int off = 1; off < 1024; off <<= 1) {
        int u = (t >= off) ? sd[t - off] : 0;
        __syncthreads();
        sd[t] += u;
        __syncthreads();
    }
    if (i < n) data[i] = sd[t] - v;
    if (t == 1023) bsum[blockIdx.x] = sd[1023];
}

// ---- scan phase 2: single-block exclusive scan of bsum (nb <= 1024)
__global__ __launch_bounds__(1024) void k_scan2(int* bsum, int nb, int* total) {
    __shared__ int sd[1024];
    int t = threadIdx.x;
    int v = (t < nb) ? bsum[t] : 0;
    sd[t] = v;
    __syncthreads();
    for (int off = 1; off < 1024; off <<= 1) {
        int u = (t >= off) ? sd[t - off] : 0;
        __syncthreads();
        sd[t] += u;
        __syncthreads();
    }
    if (t < nb) bsum[t] = sd[t] - v;
    if (t == 1023) *total = sd[1023];
}

// ---- level-1 scatter into bucket order via LDS cursors (disjoint regions)
// cur[i] = H[i*NBLK+blk] + bsum[i]  (scan3 folded in; NBLK==1024 so >>10 == i)
// pairs2[pos] = { src | (c&127)<<17 , weight } — one aligned 8B store/edge.
__global__ __launch_bounds__(256) void k_sort1b(const int* __restrict__ row,
                                                const int* __restrict__ col,
                                                const float* __restrict__ ew,
                                                const int* __restrict__ Hs,
                                                const int* __restrict__ bsum,
                                                int2* __restrict__ pairs2,
                                                int E, int NB, int chunk) {
    __shared__ int cur[MAXNB];
    int t = threadIdx.x, blk = blockIdx.x;
    for (int i = t; i < NB; i += 256) cur[i] = Hs[(size_t)i * NBLK + blk] + bsum[i];
    __syncthreads();
    int s = blk * chunk, e1 = min(s + chunk, E);
    for (int e = s + t; e < e1; e += 256) {
        int c = col[e];
        int pos = atomicAdd(&cur[c >> BSH], 1);
        pairs2[pos] = make_int2(row[e] | ((c & 127) << 17), __float_as_int(ew[e]));
    }
}

// ---- level-2: per-bucket node sort + rowptr + degree (dis), LDS only.
// pairs output = {src, weight} (norm computed later in k_agg).
__global__ __launch_bounds__(256) void k_sort2(const int* __restrict__ Hs,
                                               const int* __restrict__ bsum,
                                               const int2* __restrict__ pairs2,
                                               int2* __restrict__ pairs,
                                               int* __restrict__ rowptr,
                                               float* __restrict__ dis,
                                               int E, int N, int NB) {
    __shared__ int hist[128];
    __shared__ int pref[128];
    __shared__ float wsum[128];
    int b = blockIdx.x, t = threadIdx.x;
    int n0 = b << BSH;
    int s = Hs[(size_t)b * NBLK] + bsum[b];
    int e1 = (b + 1 < NB) ? Hs[(size_t)(b + 1) * NBLK] + bsum[b + 1] : E;
    if (t < 128) { hist[t] = 0; wsum[t] = 0.f; }
    __syncthreads();
    for (int e = s + t; e < e1; e += 256)
        atomicAdd(&hist[(unsigned)pairs2[e].x >> 17], 1);
    __syncthreads();
    if (t < 128) pref[t] = hist[t];
    __syncthreads();
    for (int off = 1; off < 128; off <<= 1) {
        int v = 0;
        if (t < 128 && t >= off) v = pref[t - off];
        __syncthreads();
        if (t < 128) pref[t] += v;
        __syncthreads();
    }
    if (t < 128) {
        int excl = pref[t] - hist[t];
        int node = n0 + t;
        if (node < N) rowptr[node] = s + excl;
        hist[t] = s + excl;  // cursor
    }
    if (b == NB - 1 && t == 0) rowptr[N] = E;
    __syncthreads();
    for (int e = s + t; e < e1; e += 256) {
        int2 pr = pairs2[e];
        int li = (unsigned)pr.x >> 17;
        int pos = atomicAdd(&hist[li], 1);
        pairs[pos] = make_int2(pr.x & 0x1FFFF, pr.y);
        atomicAdd(&wsum[li], __int_as_float(pr.y));
    }
    __syncthreads();
    if (t < 128 && n0 + t < N) dis[n0 + t] = rsqrtf(1.0f + wsum[t]);
}

// Y[N,128](bf16) = X[N,128](f32) @ W[128,128](f32) via bf16 MFMA.
// 128 rows/block, 8 waves; W^T staged to LDS as bf16 once per block.
__global__ __launch_bounds__(512) void k_gemm(const float* __restrict__ X,
                                              const float* __restrict__ W,
                                              unsigned short* __restrict__ Y, int N) {
    __shared__ unsigned short Wt[128 * LDW];
    int tid = threadIdx.x;
    for (int i = tid; i < 4096; i += 512) {  // i indexes float4 of W[k][c]
        float4 v = ((const float4*)W)[i];
        int k = i >> 5;
        int c = (i & 31) * 4;
        Wt[(c + 0) * LDW + k] = f2bf(v.x);
        Wt[(c + 1) * LDW + k] = f2bf(v.y);
        Wt[(c + 2) * LDW + k] = f2bf(v.z);
        Wt[(c + 3) * LDW + k] = f2bf(v.w);
    }
    __syncthreads();
    int w = tid >> 6, lane = tid & 63;
    int l15 = lane & 15, kg = lane >> 4;
    int r = blockIdx.x * 128 + w * 16 + l15;  // A-row this lane loads
    f32x4 acc[8];
#pragma unroll
    for (int ct = 0; ct < 8; ++ct) acc[ct] = (f32x4){0.f, 0.f, 0.f, 0.f};
#pragma unroll
    for (int kb = 0; kb < 128; kb += 32) {
        union { unsigned u[4]; bf16x8 v; } a;
        if (r < N) {
            const float4* xp = (const float4*)(X + (size_t)r * CH + kb + kg * 8);
            float4 x0 = xp[0], x1 = xp[1];
            a.u[0] = ((unsigned)f2bf(x0.y) << 16) | f2bf(x0.x);
            a.u[1] = ((unsigned)f2bf(x0.w) << 16) | f2bf(x0.z);
            a.u[2] = ((unsigned)f2bf(x1.y) << 16) | f2bf(x1.x);
            a.u[3] = ((unsigned)f2bf(x1.w) << 16) | f2bf(x1.z);
        } else {
            a.u[0] = a.u[1] = a.u[2] = a.u[3] = 0;
        }
#pragma unroll
        for (int ct = 0; ct < 8; ++ct) {
            bf16x8 b = *(const bf16x8*)&Wt[(ct * 16 + l15) * LDW + kb + kg * 8];
            acc[ct] = __builtin_amdgcn_mfma_f32_16x16x32_bf16(a.v, b, acc[ct], 0, 0, 0);
        }
    }
    // C/D layout: col = lane&15, row = kg*4 + j
    int orow = blockIdx.x * 128 + w * 16 + kg * 4;
#pragma unroll
    for (int ct = 0; ct < 8; ++ct) {
#pragma unroll
        for (int j = 0; j < 4; ++j) {
            int rr = orow + j;
            if (rr < N) Y[(size_t)rr * CH + ct * 16 + l15] = f2bf(acc[ct][j]);
        }
    }
}

// One wave per node: out = relu( dn^2*xw[n] + sum_e (dn*w_e*dis[src_e])*xw[src_e] + b ).
// pairs = {src, w}; norm computed inline (dis is L2-resident, loads are uniform).
__global__ __launch_bounds__(64) void k_agg(const unsigned int* __restrict__ XW,
                                            const float* __restrict__ dis,
                                            const int* __restrict__ rowptr,
                                            const int2* __restrict__ pairs,
                                            const float* __restrict__ bias,
                                            float* __restrict__ OUT, int N) {
    int n = blockIdx.x;
    if (n >= N) return;
    int lane = threadIdx.x;
    float dn = dis[n];
    float sn = dn * dn;
    unsigned a = XW[(size_t)n * 64 + lane];
    float ax = bflo(a) * sn;
    float ay = bfhi(a) * sn;
    int e0 = rowptr[n], e1 = rowptr[n + 1];
    int e = e0;
    for (; e + 8 <= e1; e += 8) {
        int2 p0 = pairs[e],     p1 = pairs[e + 1], p2 = pairs[e + 2], p3 = pairs[e + 3];
        int2 p4 = pairs[e + 4], p5 = pairs[e + 5], p6 = pairs[e + 6], p7 = pairs[e + 7];
        unsigned v0 = XW[(size_t)p0.x * 64 + lane];
        unsigned v1 = XW[(size_t)p1.x * 64 + lane];
        unsigned v2 = XW[(size_t)p2.x * 64 + lane];
        unsigned v3 = XW[(size_t)p3.x * 64 + lane];
        unsigned v4 = XW[(size_t)p4.x * 64 + lane];
        unsigned v5 = XW[(size_t)p5.x * 64 + lane];
        unsigned v6 = XW[(size_t)p6.x * 64 + lane];
        unsigned v7 = XW[(size_t)p7.x * 64 + lane];
        float n0 = dn * __int_as_float(p0.y) * dis[p0.x];
        float n1 = dn * __int_as_float(p1.y) * dis[p1.x];
        float n2 = dn * __int_as_float(p2.y) * dis[p2.x];
        float n3 = dn * __int_as_float(p3.y) * dis[p3.x];
        float n4 = dn * __int_as_float(p4.y) * dis[p4.x];
        float n5 = dn * __int_as_float(p5.y) * dis[p5.x];
        float n6 = dn * __int_as_float(p6.y) * dis[p6.x];
        float n7 = dn * __int_as_float(p7.y) * dis[p7.x];
        ax += n0 * bflo(v0) + n1 * bflo(v1) + n2 * bflo(v2) + n3 * bflo(v3)
            + n4 * bflo(v4) + n5 * bflo(v5) + n6 * bflo(v6) + n7 * bflo(v7);
        ay += n0 * bfhi(v0) + n1 * bfhi(v1) + n2 * bfhi(v2) + n3 * bfhi(v3)
            + n4 * bfhi(v4) + n5 * bfhi(v5) + n6 * bfhi(v6) + n7 * bfhi(v7);
    }
    for (; e < e1; ++e) {
        int2 p = pairs[e];
        unsigned v = XW[(size_t)p.x * 64 + lane];
        float nn = dn * __int_as_float(p.y) * dis[p.x];
        ax += nn * bflo(v);
        ay += nn * bfhi(v);
    }
    float2 b = ((const float2*)bias)[lane];
    ax = fmaxf(ax + b.x, 0.f);
    ay = fmaxf(ay + b.y, 0.f);
    ((float2*)OUT)[(size_t)n * 64 + lane] = make_float2(ax, ay);
}

__device__ __forceinline__ int lowerb(const int* a, int n, int v) {
    int lo = 0, hi = n;
    while (lo < hi) {
        int m = (lo + hi) >> 1;
        if (a[m] < v) lo = m + 1; else hi = m;
    }
    return lo;
}

// Stage 1: 64 graphs x PCH chunks, partial channel sums.
__global__ __launch_bounds__(128) void k_pool1(const float* __restrict__ H,
                                               const int* __restrict__ batch,
                                               float* __restrict__ partial, int N) {
    __shared__ int ss[2];
    int g = blockIdx.x / PCH;
    int k = blockIdx.x % PCH;
    if (threadIdx.x == 0) {
        ss[0] = lowerb(batch, N, g);
        ss[1] = lowerb(batch, N, g + 1);
    }
    __syncthreads();
    int s = ss[0], len = ss[1] - ss[0];
    int cs = s + (int)(((long long)len * k) / PCH);
    int ce = s + (int)(((long long)len * (k + 1)) / PCH);
    int ch = threadIdx.x;
    float a0 = 0.f, a1 = 0.f;
    int n = cs;
    for (; n + 2 <= ce; n += 2) {
        a0 += H[(size_t)(n + 0) * CH + ch];
        a1 += H[(size_t)(n + 1) * CH + ch];
    }
    for (; n < ce; ++n) a0 += H[(size_t)n * CH + ch];
    partial[(size_t)blockIdx.x * CH + ch] = a0 + a1;
}

// Stage 2: reduce PCH partials per graph, divide by count.
__global__ __launch_bounds__(128) void k_pool2(const float* __restrict__ partial,
                                               const int* __restrict__ batch,
                                               float* __restrict__ P, int N) {
    __shared__ int ss[2];
    int g = blockIdx.x;
    if (threadIdx.x == 0) {
        ss[0] = lowerb(batch, N, g);
        ss[1] = lowerb(batch, N, g + 1);
    }
    __syncthreads();
    int ch = threadIdx.x;
    float a = 0.f;
#pragma unroll
    for (int k = 0; k < PCH; ++k) a += partial[(size_t)(g * PCH + k) * CH + ch];
    float c = (float)(ss[1] - ss[0]);
    P[(size_t)g * CH + ch] = a / fmaxf(c, 1.f);
}

extern "C" void kernel_launch(void* const* d_in, const int* in_sizes, int n_in,
                              void* d_out, int out_size, void* d_ws, size_t ws_size,
                              hipStream_t stream) {
    const float* x     = (const float*)d_in[0];
    const int*   ei    = (const int*)d_in[1];
    const float* ew    = (const float*)d_in[2];
    const int*   batch = (const int*)d_in[3];
    const float* W1    = (const float*)d_in[4];
    const float* b1    = (const float*)d_in[5];
    const float* W2    = (const float*)d_in[6];
    const float* b2    = (const float*)d_in[7];

    int N = in_sizes[0] / CH;   // 50000
    int E = in_sizes[1] / 2;    // 1600000
    const int* row = ei;
    const int* col = ei + E;

    float* out    = (float*)d_out;
    float* h      = out;
    float* pooled = out + (size_t)N * CH;

    int NB    = (N + 127) >> BSH;          // 391
    int chunk = (E + NBLK - 1) / NBLK;     // 1563
    int n2    = NB * NBLK;                 // 400384

    // ws: dis | rowptr | H(n2+1; partial aliases) | bsum | pairs | xw(pairs2 aliases)
    char* wsb = (char*)d_ws;
    size_t oN  = ((size_t)N * 4 + 255) & ~(size_t)255;
    size_t oN1 = ((size_t)(N + 1) * 4 + 255) & ~(size_t)255;
    size_t oH  = ((size_t)(n2 + 1) * 4 + 255) & ~(size_t)255;
    size_t oB  = 4096;
    size_t oE2 = ((size_t)E * 8 + 255) & ~(size_t)255;
    float* dis    = (float*)wsb;
    int*   rowptr = (int*)(wsb + oN);
    int*   H      = (int*)(wsb + oN + oN1);
    int*   bsum   = (int*)(wsb + oN + oN1 + oH);
    int2*  pairs  = (int2*)(wsb + oN + oN1 + oH + oB);
    unsigned short* xw = (unsigned short*)(wsb + oN + oN1 + oH + oB + oE2);
    int2*  pairs2 = (int2*)xw;     // E*8 = 12.8MB == N*CH*2; dead before k_gemm
    float* partial = (float*)H;    // H dead after sort2; 1MB <= 1.6MB

    int sb2 = (n2 + 1023) / 1024;  // 391 (== NB, since NBLK == 1024)

    // ---- CSR build: two-level LDS counting sort (no global atomics) ----
    k_sort1a<<<NBLK, 256, 0, stream>>>(col, H, E, NB, chunk);
    k_scan1<<<sb2, 1024, 0, stream>>>(H, bsum, n2);
    k_scan2<<<1, 1024, 0, stream>>>(bsum, sb2, H + n2);
    k_sort1b<<<NBLK, 256, 0, stream>>>(row, col, ew, H, bsum, pairs2, E, NB, chunk);
    k_sort2<<<NB, 256, 0, stream>>>(H, bsum, pairs2, pairs, rowptr, dis, E, N, NB);

    int gb = (N + 127) / 128;
    // ---- layer 1 ----
    k_gemm<<<gb, 512, 0, stream>>>(x, W1, xw, N);
    k_agg<<<N, 64, 0, stream>>>((const unsigned int*)xw, dis, rowptr, pairs, b1, h, N);
    // ---- layer 2 ----
    k_gemm<<<gb, 512, 0, stream>>>(h, W2, xw, N);
    k_agg<<<N, 64, 0, stream>>>((const unsigned int*)xw, dis, rowptr, pairs, b2, h, N);
    // ---- mean pool (two-stage) ----
    k_pool1<<<64 * PCH, 128, 0, stream>>>(h, batch, partial, N);
    k_pool2<<<64, 128, 0, stream>>>(partial, batch, pooled, N);
}

// Round 9
// 223.750 us; speedup vs baseline: 2.1162x; 1.0054x over previous
//
#include <hip/hip_runtime.h>
#include <hip/hip_fp16.h>

// GCNEncoder: two GCNConv(+relu) layers + global mean pool.
// N=50000 nodes, E=1.6M edges, 128 ch, 64 graphs.
// R9: packed 4B edge records {f16 norm/w :15 | src:17}. sort2 emits {f16(w),src};
// k_norm RMWs in-place to {f16(norm),src}; k_agg has ONE random gather per edge
// (R8's inline dis[] lookup was a dependent-load latency chain: 53->60us).

#define CH 128
#define BSH 7         // 128 nodes per bucket
#define NBLK 1024     // level-1 edge-chunk blocks
#define MAXNB 512     // LDS histogram capacity (NB = ceil(N/128) = 391)
#define PCH 32        // pool chunks per graph
#define LDW 136       // Wt LDS stride

typedef __attribute__((ext_vector_type(8))) short bf16x8;
typedef __attribute__((ext_vector_type(4))) float f32x4;

static __device__ __forceinline__ unsigned short f2bf(float f) {
    unsigned u = __float_as_uint(f);
    unsigned r = (u + 0x7FFF + ((u >> 16) & 1)) >> 16;  // RNE
    return (unsigned short)r;
}
static __device__ __forceinline__ float bflo(unsigned v) { return __uint_as_float(v << 16); }
static __device__ __forceinline__ float bfhi(unsigned v) { return __uint_as_float(v & 0xFFFF0000u); }
static __device__ __forceinline__ float f16u(unsigned bits15) {
    __half_raw hr; hr.x = (unsigned short)(bits15 & 0x7FFF);
    return __half2float(*reinterpret_cast<__half*>(&hr));
}
static __device__ __forceinline__ unsigned u16f(float f) {  // f >= 0
    __half hh = __float2half(f);
    return (unsigned)(*reinterpret_cast<unsigned short*>(&hh)) & 0x7FFF;
}

// ---- level-1 count: per-(bucket, chunk-block) histogram, LDS atomics only
__global__ __launch_bounds__(256) void k_sort1a(const int* __restrict__ col,
                                                int* __restrict__ H, int E, int NB, int chunk) {
    __shared__ int hist[MAXNB];
    int t = threadIdx.x, blk = blockIdx.x;
    for (int i = t; i < NB; i += 256) hist[i] = 0;
    __syncthreads();
    int s = blk * chunk, e1 = min(s + chunk, E);
    for (int e = s + t; e < e1; e += 256) atomicAdd(&hist[col[e] >> BSH], 1);
    __syncthreads();
    for (int i = t; i < NB; i += 256) H[(size_t)i * NBLK + blk] = hist[i];
}

// ---- scan phase 1: block-local exclusive in place, block totals to bsum
__global__ __launch_bounds__(1024) void k_scan1(int* __restrict__ data,
                                                int* __restrict__ bsum, int n) {
    __shared__ int sd[1024];
    int t = threadIdx.x;
    int i = blockIdx.x * 1024 + t;
    int v = (i < n) ? data[i] : 0;
    sd[t] = v;
    __syncthreads();
    for (int off = 1; off < 1024; off <<= 1) {
        int u = (t >= off) ? sd[t - off] : 0;
        __syncthreads();
        sd[t] += u;
        __syncthreads();
    }
    if (i < n) data[i] = sd[t] - v;
    if (t == 1023) bsum[blockIdx.x] = sd[1023];
}

// ---- scan phase 2: single-block exclusive scan of bsum (nb <= 1024)
__global__ __launch_bounds__(1024) void k_scan2(int* bsum, int nb, int* total) {
    __shared__ int sd[1024];
    int t = threadIdx.x;
    int v = (t < nb) ? bsum[t] : 0;
    sd[t] = v;
    __syncthreads();
    for (int off = 1; off < 1024; off <<= 1) {
        int u = (t >= off) ? sd[t - off] : 0;
        __syncthreads();
        sd[t] += u;
        __syncthreads();
    }
    if (t < nb) bsum[t] = sd[t] - v;
    if (t == 1023) *total = sd[1023];
}

// ---- level-1 scatter into bucket order via LDS cursors (disjoint regions)
__global__ __launch_bounds__(256) void k_sort1b(const int* __restrict__ row,
                                                const int* __restrict__ col,
                                                const float* __restrict__ ew,
                                                const int* __restrict__ Hs,
                                                const int* __restrict__ bsum,
                                                int2* __restrict__ pairs2,
                                                int E, int NB, int chunk) {
    __shared__ int cur[MAXNB];
    int t = threadIdx.x, blk = blockIdx.x;
    for (int i = t; i < NB; i += 256) cur[i] = Hs[(size_t)i * NBLK + blk] + bsum[i];
    __syncthreads();
    int s = blk * chunk, e1 = min(s + chunk, E);
    for (int e = s + t; e < e1; e += 256) {
        int c = col[e];
        int pos = atomicAdd(&cur[c >> BSH], 1);
        pairs2[pos] = make_int2(row[e] | ((c & 127) << 17), __float_as_int(ew[e]));
    }
}

// ---- level-2: per-bucket node sort + rowptr + degree (dis), LDS only.
// Output: epk[pos] = { f16(w):15 | src:17 } (4B per edge).
__global__ __launch_bounds__(256) void k_sort2(const int* __restrict__ Hs,
                                               const int* __restrict__ bsum,
                                               const int2* __restrict__ pairs2,
                                               unsigned* __restrict__ epk,
                                               int* __restrict__ rowptr,
                                               float* __restrict__ dis,
                                               int E, int N, int NB) {
    __shared__ int hist[128];
    __shared__ int pref[128];
    __shared__ float wsum[128];
    int b = blockIdx.x, t = threadIdx.x;
    int n0 = b << BSH;
    int s = Hs[(size_t)b * NBLK] + bsum[b];
    int e1 = (b + 1 < NB) ? Hs[(size_t)(b + 1) * NBLK] + bsum[b + 1] : E;
    if (t < 128) { hist[t] = 0; wsum[t] = 0.f; }
    __syncthreads();
    for (int e = s + t; e < e1; e += 256)
        atomicAdd(&hist[(unsigned)pairs2[e].x >> 17], 1);
    __syncthreads();
    if (t < 128) pref[t] = hist[t];
    __syncthreads();
    for (int off = 1; off < 128; off <<= 1) {
        int v = 0;
        if (t < 128 && t >= off) v = pref[t - off];
        __syncthreads();
        if (t < 128) pref[t] += v;
        __syncthreads();
    }
    if (t < 128) {
        int excl = pref[t] - hist[t];
        int node = n0 + t;
        if (node < N) rowptr[node] = s + excl;
        hist[t] = s + excl;  // cursor
    }
    if (b == NB - 1 && t == 0) rowptr[N] = E;
    __syncthreads();
    for (int e = s + t; e < e1; e += 256) {
        int2 pr = pairs2[e];
        int li = (unsigned)pr.x >> 17;
        float w = __int_as_float(pr.y);
        int pos = atomicAdd(&hist[li], 1);
        epk[pos] = (unsigned)(pr.x & 0x1FFFF) | (u16f(w) << 17);
        atomicAdd(&wsum[li], w);
    }
    __syncthreads();
    if (t < 128 && n0 + t < N) dis[n0 + t] = rsqrtf(1.0f + wsum[t]);
}

// In-place: epk[e] {f16(w),src} -> {f16(dn*w*dis[src]), src}
__global__ __launch_bounds__(64) void k_norm(const int* __restrict__ rowptr,
                                             unsigned* __restrict__ epk,
                                             const float* __restrict__ dis, int N) {
    int n = blockIdx.x;
    int lane = threadIdx.x;
    float dn = dis[n];
    int e0 = rowptr[n], e1 = rowptr[n + 1];
    for (int e = e0 + lane; e < e1; e += 64) {
        unsigned v = epk[e];
        unsigned src = v & 0x1FFFF;
        float nn = dn * f16u(v >> 17) * dis[src];
        epk[e] = src | (u16f(nn) << 17);
    }
}

// Y[N,128](bf16) = X[N,128](f32) @ W[128,128](f32) via bf16 MFMA.
__global__ __launch_bounds__(512) void k_gemm(const float* __restrict__ X,
                                              const float* __restrict__ W,
                                              unsigned short* __restrict__ Y, int N) {
    __shared__ unsigned short Wt[128 * LDW];
    int tid = threadIdx.x;
    for (int i = tid; i < 4096; i += 512) {  // i indexes float4 of W[k][c]
        float4 v = ((const float4*)W)[i];
        int k = i >> 5;
        int c = (i & 31) * 4;
        Wt[(c + 0) * LDW + k] = f2bf(v.x);
        Wt[(c + 1) * LDW + k] = f2bf(v.y);
        Wt[(c + 2) * LDW + k] = f2bf(v.z);
        Wt[(c + 3) * LDW + k] = f2bf(v.w);
    }
    __syncthreads();
    int w = tid >> 6, lane = tid & 63;
    int l15 = lane & 15, kg = lane >> 4;
    int r = blockIdx.x * 128 + w * 16 + l15;
    f32x4 acc[8];
#pragma unroll
    for (int ct = 0; ct < 8; ++ct) acc[ct] = (f32x4){0.f, 0.f, 0.f, 0.f};
#pragma unroll
    for (int kb = 0; kb < 128; kb += 32) {
        union { unsigned u[4]; bf16x8 v; } a;
        if (r < N) {
            const float4* xp = (const float4*)(X + (size_t)r * CH + kb + kg * 8);
            float4 x0 = xp[0], x1 = xp[1];
            a.u[0] = ((unsigned)f2bf(x0.y) << 16) | f2bf(x0.x);
            a.u[1] = ((unsigned)f2bf(x0.w) << 16) | f2bf(x0.z);
            a.u[2] = ((unsigned)f2bf(x1.y) << 16) | f2bf(x1.x);
            a.u[3] = ((unsigned)f2bf(x1.w) << 16) | f2bf(x1.z);
        } else {
            a.u[0] = a.u[1] = a.u[2] = a.u[3] = 0;
        }
#pragma unroll
        for (int ct = 0; ct < 8; ++ct) {
            bf16x8 b = *(const bf16x8*)&Wt[(ct * 16 + l15) * LDW + kb + kg * 8];
            acc[ct] = __builtin_amdgcn_mfma_f32_16x16x32_bf16(a.v, b, acc[ct], 0, 0, 0);
        }
    }
    int orow = blockIdx.x * 128 + w * 16 + kg * 4;
#pragma unroll
    for (int ct = 0; ct < 8; ++ct) {
#pragma unroll
        for (int j = 0; j < 4; ++j) {
            int rr = orow + j;
            if (rr < N) Y[(size_t)rr * CH + ct * 16 + l15] = f2bf(acc[ct][j]);
        }
    }
}

// One wave per node: out = relu( dn^2*xw[n] + sum_e nn_e*xw[src_e] + b ).
// epk = {f16 norm | src}; exactly one random gather per edge.
__global__ __launch_bounds__(64) void k_agg(const unsigned int* __restrict__ XW,
                                            const float* __restrict__ dis,
                                            const int* __restrict__ rowptr,
                                            const unsigned* __restrict__ epk,
                                            const float* __restrict__ bias,
                                            float* __restrict__ OUT, int N) {
    int n = blockIdx.x;
    if (n >= N) return;
    int lane = threadIdx.x;
    float dn = dis[n];
    float sn = dn * dn;
    unsigned a = XW[(size_t)n * 64 + lane];
    float ax = bflo(a) * sn;
    float ay = bfhi(a) * sn;
    int e0 = rowptr[n], e1 = rowptr[n + 1];
    int e = e0;
    for (; e + 8 <= e1; e += 8) {
        unsigned p0 = epk[e],     p1 = epk[e + 1], p2 = epk[e + 2], p3 = epk[e + 3];
        unsigned p4 = epk[e + 4], p5 = epk[e + 5], p6 = epk[e + 6], p7 = epk[e + 7];
        unsigned v0 = XW[(size_t)(p0 & 0x1FFFF) * 64 + lane];
        unsigned v1 = XW[(size_t)(p1 & 0x1FFFF) * 64 + lane];
        unsigned v2 = XW[(size_t)(p2 & 0x1FFFF) * 64 + lane];
        unsigned v3 = XW[(size_t)(p3 & 0x1FFFF) * 64 + lane];
        unsigned v4 = XW[(size_t)(p4 & 0x1FFFF) * 64 + lane];
        unsigned v5 = XW[(size_t)(p5 & 0x1FFFF) * 64 + lane];
        unsigned v6 = XW[(size_t)(p6 & 0x1FFFF) * 64 + lane];
        unsigned v7 = XW[(size_t)(p7 & 0x1FFFF) * 64 + lane];
        float n0 = f16u(p0 >> 17), n1 = f16u(p1 >> 17);
        float n2 = f16u(p2 >> 17), n3 = f16u(p3 >> 17);
        float n4 = f16u(p4 >> 17), n5 = f16u(p5 >> 17);
        float n6 = f16u(p6 >> 17), n7 = f16u(p7 >> 17);
        ax += n0 * bflo(v0) + n1 * bflo(v1) + n2 * bflo(v2) + n3 * bflo(v3)
            + n4 * bflo(v4) + n5 * bflo(v5) + n6 * bflo(v6) + n7 * bflo(v7);
        ay += n0 * bfhi(v0) + n1 * bfhi(v1) + n2 * bfhi(v2) + n3 * bfhi(v3)
            + n4 * bfhi(v4) + n5 * bfhi(v5) + n6 * bfhi(v6) + n7 * bfhi(v7);
    }
    for (; e < e1; ++e) {
        unsigned p = epk[e];
        unsigned v = XW[(size_t)(p & 0x1FFFF) * 64 + lane];
        float nn = f16u(p >> 17);
        ax += nn * bflo(v);
        ay += nn * bfhi(v);
    }
    float2 b = ((const float2*)bias)[lane];
    ax = fmaxf(ax + b.x, 0.f);
    ay = fmaxf(ay + b.y, 0.f);
    ((float2*)OUT)[(size_t)n * 64 + lane] = make_float2(ax, ay);
}

__device__ __forceinline__ int lowerb(const int* a, int n, int v) {
    int lo = 0, hi = n;
    while (lo < hi) {
        int m = (lo + hi) >> 1;
        if (a[m] < v) lo = m + 1; else hi = m;
    }
    return lo;
}

// Stage 1: 64 graphs x PCH chunks, partial channel sums.
__global__ __launch_bounds__(128) void k_pool1(const float* __restrict__ H,
                                               const int* __restrict__ batch,
                                               float* __restrict__ partial, int N) {
    __shared__ int ss[2];
    int g = blockIdx.x / PCH;
    int k = blockIdx.x % PCH;
    if (threadIdx.x == 0) {
        ss[0] = lowerb(batch, N, g);
        ss[1] = lowerb(batch, N, g + 1);
    }
    __syncthreads();
    int s = ss[0], len = ss[1] - ss[0];
    int cs = s + (int)(((long long)len * k) / PCH);
    int ce = s + (int)(((long long)len * (k + 1)) / PCH);
    int ch = threadIdx.x;
    float a0 = 0.f, a1 = 0.f;
    int n = cs;
    for (; n + 2 <= ce; n += 2) {
        a0 += H[(size_t)(n + 0) * CH + ch];
        a1 += H[(size_t)(n + 1) * CH + ch];
    }
    for (; n < ce; ++n) a0 += H[(size_t)n * CH + ch];
    partial[(size_t)blockIdx.x * CH + ch] = a0 + a1;
}

// Stage 2: reduce PCH partials per graph, divide by count.
__global__ __launch_bounds__(128) void k_pool2(const float* __restrict__ partial,
                                               const int* __restrict__ batch,
                                               float* __restrict__ P, int N) {
    __shared__ int ss[2];
    int g = blockIdx.x;
    if (threadIdx.x == 0) {
        ss[0] = lowerb(batch, N, g);
        ss[1] = lowerb(batch, N, g + 1);
    }
    __syncthreads();
    int ch = threadIdx.x;
    float a = 0.f;
#pragma unroll
    for (int k = 0; k < PCH; ++k) a += partial[(size_t)(g * PCH + k) * CH + ch];
    float c = (float)(ss[1] - ss[0]);
    P[(size_t)g * CH + ch] = a / fmaxf(c, 1.f);
}

extern "C" void kernel_launch(void* const* d_in, const int* in_sizes, int n_in,
                              void* d_out, int out_size, void* d_ws, size_t ws_size,
                              hipStream_t stream) {
    const float* x     = (const float*)d_in[0];
    const int*   ei    = (const int*)d_in[1];
    const float* ew    = (const float*)d_in[2];
    const int*   batch = (const int*)d_in[3];
    const float* W1    = (const float*)d_in[4];
    const float* b1    = (const float*)d_in[5];
    const float* W2    = (const float*)d_in[6];
    const float* b2    = (const float*)d_in[7];

    int N = in_sizes[0] / CH;   // 50000
    int E = in_sizes[1] / 2;    // 1600000
    const int* row = ei;
    const int* col = ei + E;

    float* out    = (float*)d_out;
    float* h      = out;
    float* pooled = out + (size_t)N * CH;

    int NB    = (N + 127) >> BSH;          // 391
    int chunk = (E + NBLK - 1) / NBLK;     // 1563
    int n2    = NB * NBLK;                 // 400384

    // ws: dis | rowptr | H(n2+1; partial aliases) | bsum | epk(E*4) | xw(pairs2 aliases)
    char* wsb = (char*)d_ws;
    size_t oN  = ((size_t)N * 4 + 255) & ~(size_t)255;
    size_t oN1 = ((size_t)(N + 1) * 4 + 255) & ~(size_t)255;
    size_t oH  = ((size_t)(n2 + 1) * 4 + 255) & ~(size_t)255;
    size_t oB  = 4096;
    size_t oE1 = ((size_t)E * 4 + 255) & ~(size_t)255;
    float* dis    = (float*)wsb;
    int*   rowptr = (int*)(wsb + oN);
    int*   H      = (int*)(wsb + oN + oN1);
    int*   bsum   = (int*)(wsb + oN + oN1 + oH);
    unsigned* epk = (unsigned*)(wsb + oN + oN1 + oH + oB);
    unsigned short* xw = (unsigned short*)(wsb + oN + oN1 + oH + oB + oE1);
    int2*  pairs2 = (int2*)xw;     // E*8 = 12.8MB == N*CH*2; dead before k_gemm
    float* partial = (float*)H;    // H dead after sort2; 1MB <= 1.6MB

    int sb2 = (n2 + 1023) / 1024;  // 391

    // ---- CSR build: two-level LDS counting sort (no global atomics) ----
    k_sort1a<<<NBLK, 256, 0, stream>>>(col, H, E, NB, chunk);
    k_scan1<<<sb2, 1024, 0, stream>>>(H, bsum, n2);
    k_scan2<<<1, 1024, 0, stream>>>(bsum, sb2, H + n2);
    k_sort1b<<<NBLK, 256, 0, stream>>>(row, col, ew, H, bsum, pairs2, E, NB, chunk);
    k_sort2<<<NB, 256, 0, stream>>>(H, bsum, pairs2, epk, rowptr, dis, E, N, NB);
    k_norm<<<N, 64, 0, stream>>>(rowptr, epk, dis, N);

    int gb = (N + 127) / 128;
    // ---- layer 1 ----
    k_gemm<<<gb, 512, 0, stream>>>(x, W1, xw, N);
    k_agg<<<N, 64, 0, stream>>>((const unsigned int*)xw, dis, rowptr, epk, b1, h, N);
    // ---- layer 2 ----
    k_gemm<<<gb, 512, 0, stream>>>(h, W2, xw, N);
    k_agg<<<N, 64, 0, stream>>>((const unsigned int*)xw, dis, rowptr, epk, b2, h, N);
    // ---- mean pool (two-stage) ----
    k_pool1<<<64 * PCH, 128, 0, stream>>>(h, batch, partial, N);
    k_pool2<<<64, 128, 0, stream>>>(partial, batch, pooled, N);
}